// Round 1
// baseline (253.158 us; speedup 1.0000x reference)
//
#include <hip/hip_runtime.h>

// ROI crop_and_resize: feature_map [8,64,64,256] f32 NHWC, rois [8,128,4] f32
// out [1024,14,14,256] f32.
// One output pixel (n,i,j) handled by 64 consecutive lanes (one wave),
// each lane covering 4 channels via float4. Coalesced reads/writes.

#define B_   8
#define H_   64
#define W_   64
#define C4_  64      // 256 channels / 4
#define NROI 128
#define CH_  14
#define CW_  14
#define NPIX (B_ * NROI * CH_ * CW_)   // 1024*14*14 = 200704

__global__ __launch_bounds__(256) void roi_crop_resize_kernel(
    const float4* __restrict__ fm,     // [8*64*64*64] float4
    const float*  __restrict__ rois,   // [1024*4]
    float4*       __restrict__ out)    // [200704*64] float4
{
    int gid = blockIdx.x * blockDim.x + threadIdx.x;
    int cg  = gid & (C4_ - 1);     // channel group 0..63
    int pix = gid >> 6;            // pixel index
    // grid sized exactly; no bounds check needed but keep cheap guard off

    int j   = pix % CW_;
    int t   = pix / CW_;
    int i   = t % CH_;
    int n   = t / CH_;             // roi index 0..1023
    int b   = n >> 7;              // batch = n / 128

    const float* box = rois + n * 4;
    float y1 = box[0], x1 = box[1], y2 = box[2], x2 = box[3];

    const float Hm1 = (float)(H_ - 1);
    const float Wm1 = (float)(W_ - 1);

    float h_scale = (y2 - y1) * Hm1 / (float)(CH_ - 1);
    float w_scale = (x2 - x1) * Wm1 / (float)(CW_ - 1);

    float in_y = y1 * Hm1 + (float)i * h_scale;
    float in_x = x1 * Wm1 + (float)j * w_scale;

    bool valid = (in_y >= 0.0f) & (in_y <= Hm1) & (in_x >= 0.0f) & (in_x <= Wm1);

    float fy = floorf(in_y);
    float fx = floorf(in_x);
    float cy = ceilf(in_y);
    float cx = ceilf(in_x);

    int ty = (int)fminf(fmaxf(fy, 0.0f), Hm1);
    int by = (int)fminf(fmaxf(cy, 0.0f), Hm1);
    int lx = (int)fminf(fmaxf(fx, 0.0f), Wm1);
    int rx = (int)fminf(fmaxf(cx, 0.0f), Wm1);

    float yl = in_y - fy;
    float xl = in_x - fx;

    int rowT = (b * H_ + ty) * W_;
    int rowB = (b * H_ + by) * W_;

    float4 tl = fm[(rowT + lx) * C4_ + cg];
    float4 tr = fm[(rowT + rx) * C4_ + cg];
    float4 bl = fm[(rowB + lx) * C4_ + cg];
    float4 br = fm[(rowB + rx) * C4_ + cg];

    float4 o;
    {
        float top, bot;
        top = tl.x + (tr.x - tl.x) * xl;
        bot = bl.x + (br.x - bl.x) * xl;
        o.x = top + (bot - top) * yl;
        top = tl.y + (tr.y - tl.y) * xl;
        bot = bl.y + (br.y - bl.y) * xl;
        o.y = top + (bot - top) * yl;
        top = tl.z + (tr.z - tl.z) * xl;
        bot = bl.z + (br.z - bl.z) * xl;
        o.z = top + (bot - top) * yl;
        top = tl.w + (tr.w - tl.w) * xl;
        bot = bl.w + (br.w - bl.w) * xl;
        o.w = top + (bot - top) * yl;
    }

    if (!valid) { o.x = 0.0f; o.y = 0.0f; o.z = 0.0f; o.w = 0.0f; }

    out[(size_t)pix * C4_ + cg] = o;
}

extern "C" void kernel_launch(void* const* d_in, const int* in_sizes, int n_in,
                              void* d_out, int out_size, void* d_ws, size_t ws_size,
                              hipStream_t stream) {
    const float4* fm   = (const float4*)d_in[0];
    const float*  rois = (const float*)d_in[1];
    float4*       out  = (float4*)d_out;

    // total threads = NPIX * 64 = 12,845,056 ; 256/block -> 50,176 blocks (exact)
    int total_threads = NPIX * C4_;
    int block = 256;
    int grid  = total_threads / block;
    roi_crop_resize_kernel<<<grid, block, 0, stream>>>(fm, rois, out);
}

// Round 3
// 248.677 us; speedup vs baseline: 1.0180x; 1.0180x over previous
//
#include <hip/hip_runtime.h>

// ROI crop_and_resize: feature_map [8,64,64,256] f32 NHWC, rois [8,128,4] f32
// out [1024,14,14,256] f32.
// One output pixel (n,i,j) = one 64-lane wave; lane cg covers 4 channels (float4).
//
// XCD-locality swizzle: each batch image is 4 MB = exactly one XCD's L2.
// blockIdx % 8 ~ XCD (round-robin dispatch), so map blockIdx (m&7) -> batch,
// keeping each XCD's gather reads inside its own resident L2 copy of one image.
// Output stores are non-temporal so the 205 MB write stream doesn't evict fm.

#define B_   8
#define H_   64
#define W_   64
#define C4_  64      // 256 channels / 4
#define NROI 128
#define CH_  14
#define CW_  14
#define NPIX (B_ * NROI * CH_ * CW_)          // 200704
#define PIX_PER_BLOCK 4                        // 256 threads / 64 lanes
#define BLOCKS_TOTAL (NPIX / PIX_PER_BLOCK)    // 50176
#define BLOCKS_PER_BATCH (BLOCKS_TOTAL / B_)   // 6272

typedef float nfloat4 __attribute__((ext_vector_type(4)));  // native vec for nt-store

__global__ __launch_bounds__(256) void roi_crop_resize_kernel(
    const float4* __restrict__ fm,     // [8*64*64*64] float4
    const float*  __restrict__ rois,   // [1024*4]
    nfloat4*      __restrict__ out)    // [200704*64] float4
{
    // XCD swizzle: batch = blockIdx % 8, slot within batch = blockIdx / 8
    int m      = blockIdx.x;
    int xcd    = m & 7;
    int slot   = m >> 3;
    int pblock = xcd * BLOCKS_PER_BATCH + slot;   // pixel-block in [0, 50176)

    int gid = pblock * 256 + (int)threadIdx.x;
    int cg  = gid & (C4_ - 1);     // channel group 0..63 (lane id)
    int pix = gid >> 6;            // pixel index 0..200703

    int j   = pix % CW_;
    int t   = pix / CW_;
    int i   = t % CH_;
    int n   = t / CH_;             // roi index 0..1023
    int b   = n >> 7;              // batch = n / 128  (== xcd by construction)

    const float* box = rois + n * 4;
    float y1 = box[0], x1 = box[1], y2 = box[2], x2 = box[3];

    const float Hm1 = (float)(H_ - 1);
    const float Wm1 = (float)(W_ - 1);

    float h_scale = (y2 - y1) * Hm1 / (float)(CH_ - 1);
    float w_scale = (x2 - x1) * Wm1 / (float)(CW_ - 1);

    float in_y = y1 * Hm1 + (float)i * h_scale;
    float in_x = x1 * Wm1 + (float)j * w_scale;

    bool valid = (in_y >= 0.0f) & (in_y <= Hm1) & (in_x >= 0.0f) & (in_x <= Wm1);

    float fy = floorf(in_y);
    float fx = floorf(in_x);
    float cy = ceilf(in_y);
    float cx = ceilf(in_x);

    int ty = (int)fminf(fmaxf(fy, 0.0f), Hm1);
    int by = (int)fminf(fmaxf(cy, 0.0f), Hm1);
    int lx = (int)fminf(fmaxf(fx, 0.0f), Wm1);
    int rx = (int)fminf(fmaxf(cx, 0.0f), Wm1);

    float yl = in_y - fy;
    float xl = in_x - fx;

    int rowT = (b * H_ + ty) * W_;
    int rowB = (b * H_ + by) * W_;

    float4 tl = fm[(rowT + lx) * C4_ + cg];
    float4 tr = fm[(rowT + rx) * C4_ + cg];
    float4 bl = fm[(rowB + lx) * C4_ + cg];
    float4 br = fm[(rowB + rx) * C4_ + cg];

    float4 o;
    {
        float top, bot;
        top = tl.x + (tr.x - tl.x) * xl;
        bot = bl.x + (br.x - bl.x) * xl;
        o.x = top + (bot - top) * yl;
        top = tl.y + (tr.y - tl.y) * xl;
        bot = bl.y + (br.y - bl.y) * xl;
        o.y = top + (bot - top) * yl;
        top = tl.z + (tr.z - tl.z) * xl;
        bot = bl.z + (br.z - bl.z) * xl;
        o.z = top + (bot - top) * yl;
        top = tl.w + (tr.w - tl.w) * xl;
        bot = bl.w + (br.w - bl.w) * xl;
        o.w = top + (bot - top) * yl;
    }

    if (!valid) { o.x = 0.0f; o.y = 0.0f; o.z = 0.0f; o.w = 0.0f; }

    nfloat4 ov;
    ov.x = o.x; ov.y = o.y; ov.z = o.z; ov.w = o.w;
    __builtin_nontemporal_store(ov, &out[(size_t)pix * C4_ + cg]);
}

extern "C" void kernel_launch(void* const* d_in, const int* in_sizes, int n_in,
                              void* d_out, int out_size, void* d_ws, size_t ws_size,
                              hipStream_t stream) {
    const float4* fm   = (const float4*)d_in[0];
    const float*  rois = (const float*)d_in[1];
    nfloat4*      out  = (nfloat4*)d_out;

    roi_crop_resize_kernel<<<BLOCKS_TOTAL, 256, 0, stream>>>(fm, rois, out);
}